// Round 1
// baseline (296.067 us; speedup 1.0000x reference)
//
#include <hip/hip_runtime.h>

// MultiHeadedAttention (B=8, S=1024, D=512, H=8, DK=DV=64), f32 in/out.
// r8: attn barrier-free — K/V fit L2 (256KB per (b,h)), so drop LDS staging
// entirely: K/V MFMA B-frags loaded directly from global (L2-hit), K prefetched
// one tile ahead in regs, V issued at iter top, maps prefetched (unchanged).
// Zero __syncthreads in attn; LDS only the per-wave P transpose buffer.
// GEMM: dbuf single-barrier K-loop, QKV fused in one launch (unchanged).

typedef unsigned short u16;
typedef u16 u16x4 __attribute__((ext_vector_type(4)));
typedef u16 u16x8 __attribute__((ext_vector_type(8)));
typedef short s16x8 __attribute__((ext_vector_type(8)));
typedef float f32x4 __attribute__((ext_vector_type(4)));

#define SB 1024
#define DD 512
#define NEGC (-1.0e9f)

__device__ __forceinline__ float bf2f(u16 x) {
    return __uint_as_float(((unsigned)x) << 16);
}
__device__ __forceinline__ u16 f2bf(float f) {
    unsigned u = __float_as_uint(f);
    u += 0x7FFFu + ((u >> 16) & 1u);
    return (u16)(u >> 16);
}

// DPP cross-lane (16-lane row) reduce — pure VALU, no LDS pipe.
template<int CTRL>
__device__ __forceinline__ float dppf(float x) {
    return __int_as_float(__builtin_amdgcn_mov_dpp(__float_as_int(x), CTRL, 0xF, 0xF, true));
}
__device__ __forceinline__ float row16_max(float x) {
    x = fmaxf(x, dppf<0xB1>(x));
    x = fmaxf(x, dppf<0x4E>(x));
    x = fmaxf(x, dppf<0x141>(x));
    x = fmaxf(x, dppf<0x140>(x));
    return x;
}
__device__ __forceinline__ float row16_sum(float x) {
    x += dppf<0xB1>(x);
    x += dppf<0x4E>(x);
    x += dppf<0x141>(x);
    x += dppf<0x140>(x);
    return x;
}

// ---------------------------------------------------------------------------
// GEMM body: C[m][n] = (sum_k X[m][k]*W[n][k] + bias[n]) * scale
// Tile 128(M)x64(N), BK=64, 4 waves (wave-tile 32x64). Double-buffered LDS,
// ONE barrier/iter. XCD swizzle for L2 reuse of X slabs.
// ---------------------------------------------------------------------------
template<bool XF32, bool OUTF32>
__device__ __forceinline__ void gemm_body(
    const void* __restrict__ Xv, const float* __restrict__ W,
    const float* __restrict__ bias, void* __restrict__ Cv,
    int M, int N, int K, float scale)
{
    __shared__ __align__(16) u16 As[2][128][72];
    __shared__ __align__(16) u16 Bs[2][64][72];
    const int tid  = threadIdx.x;
    const int lane = tid & 63, wave = tid >> 6;
    const int l15 = lane & 15, lq = lane >> 4;

    const int l   = blockIdx.x + gridDim.x * blockIdx.y;
    const int xcd = l & 7, j = l >> 3;
    const int m0  = (xcd * (M / 128 / 8) + (j >> 3)) * 128;
    const int n0  = (j & 7) * 64;

    int xr32[8], xc32[8], xr16[4], xc16[4], wr_[4], wc_[4];
    #pragma unroll
    for (int i = 0; i < 8; ++i) {
        int c = i * 256 + tid;
        xr32[i] = c >> 4;  xc32[i] = (c & 15) * 4;
    }
    #pragma unroll
    for (int i = 0; i < 4; ++i) {
        int c = i * 256 + tid;
        xr16[i] = c >> 3;  xc16[i] = (c & 7) * 8;
        wr_[i]  = c >> 4;  wc_[i]  = (c & 15) * 4;
    }

    f32x4 xa32[8];  u16x8 xa16[4];  f32x4 wa[4];
    auto load_slab = [&](int k0) {
        if (XF32) {
            #pragma unroll
            for (int i = 0; i < 8; ++i)
                xa32[i] = *(const f32x4*)((const float*)Xv + (size_t)(m0 + xr32[i]) * K + k0 + xc32[i]);
        } else {
            #pragma unroll
            for (int i = 0; i < 4; ++i)
                xa16[i] = *(const u16x8*)((const u16*)Xv + (size_t)(m0 + xr16[i]) * K + k0 + xc16[i]);
        }
        #pragma unroll
        for (int i = 0; i < 4; ++i)
            wa[i] = *(const f32x4*)(W + (size_t)(n0 + wr_[i]) * K + k0 + wc_[i]);
    };
    auto write_lds = [&](int buf) {
        if (XF32) {
            #pragma unroll
            for (int i = 0; i < 8; ++i) {
                u16x4 t;
                #pragma unroll
                for (int e = 0; e < 4; ++e) t[e] = f2bf(xa32[i][e]);
                *(u16x4*)&As[buf][xr32[i]][xc32[i]] = t;
            }
        } else {
            #pragma unroll
            for (int i = 0; i < 4; ++i)
                *(u16x8*)&As[buf][xr16[i]][xc16[i]] = xa16[i];
        }
        #pragma unroll
        for (int i = 0; i < 4; ++i) {
            u16x4 t;
            #pragma unroll
            for (int e = 0; e < 4; ++e) t[e] = f2bf(wa[i][e]);
            *(u16x4*)&Bs[buf][wr_[i]][wc_[i]] = t;
        }
    };

    f32x4 acc[2][4] = {};
    load_slab(0);
    const int steps = K / 64;
    for (int kt = 0; kt < steps; ++kt) {
        const int buf = kt & 1;
        write_lds(buf);            // slab kt (regs from iter kt-1); buffer unread this iter
        __syncthreads();
        if (kt + 1 < steps) load_slab((kt + 1) * 64);

        #pragma unroll
        for (int ks = 0; ks < 2; ++ks) {
            s16x8 af[2], bf[4];
            #pragma unroll
            for (int mt = 0; mt < 2; ++mt)
                af[mt] = *(const s16x8*)&As[buf][wave * 32 + mt * 16 + l15][ks * 32 + lq * 8];
            #pragma unroll
            for (int nt = 0; nt < 4; ++nt)
                bf[nt] = *(const s16x8*)&Bs[buf][nt * 16 + l15][ks * 32 + lq * 8];
            #pragma unroll
            for (int mt = 0; mt < 2; ++mt)
                #pragma unroll
                for (int nt = 0; nt < 4; ++nt)
                    acc[mt][nt] = __builtin_amdgcn_mfma_f32_16x16x32_bf16(
                        af[mt], bf[nt], acc[mt][nt], 0, 0, 0);
        }
    }

    float bb[4];
    #pragma unroll
    for (int nt = 0; nt < 4; ++nt) bb[nt] = bias[n0 + nt * 16 + l15];
    #pragma unroll
    for (int mt = 0; mt < 2; ++mt) {
        #pragma unroll
        for (int r = 0; r < 4; ++r) {
            const size_t row = (size_t)(m0 + wave * 32 + mt * 16 + lq * 4 + r);
            #pragma unroll
            for (int nt = 0; nt < 4; ++nt) {
                float v = (acc[mt][nt][r] + bb[nt]) * scale;
                const size_t col = n0 + nt * 16 + l15;
                if (OUTF32) ((float*)Cv)[row * N + col] = v;
                else        ((u16*)Cv)[row * N + col] = f2bf(v);
            }
        }
    }
}

struct QKVParams {
    const float *X0, *X1, *X2;
    const float *W0, *W1, *W2;
    const float *b0, *b1, *b2;
    u16 *C0, *C1, *C2;
};

// fused Q/K/V projections: blockIdx.z selects the sub-GEMM
__global__ __launch_bounds__(256, 2) void qkv_gemm(QKVParams p) {
    const int z = blockIdx.z;
    const float* X = (z == 0) ? p.X0 : (z == 1) ? p.X1 : p.X2;
    const float* W = (z == 0) ? p.W0 : (z == 1) ? p.W1 : p.W2;
    const float* b = (z == 0) ? p.b0 : (z == 1) ? p.b1 : p.b2;
    u16* C = (z == 0) ? p.C0 : (z == 1) ? p.C1 : p.C2;
    const float scale = (z == 0) ? 0.125f : 1.0f;
    gemm_body<true, false>(X, W, b, C, 8 * SB, DD, DD, scale);
}

__global__ __launch_bounds__(256, 2) void out_gemm(
    const u16* __restrict__ X, const float* __restrict__ W,
    const float* __restrict__ bias, float* __restrict__ C) {
    gemm_body<false, true>(X, W, bias, C, 8 * SB, DD, DD, 1.0f);
}

// ---------------------------------------------------------------------------
// V transpose: Vn[b*SB+tok][h*64+dv] -> Vt[(b*8+h)*64+dv][tok]  (bf16)
// ---------------------------------------------------------------------------
__global__ __launch_bounds__(256) void vt_kernel(
    const u16* __restrict__ Vn, u16* __restrict__ Vt)
{
    __shared__ u16 Ls[64][72];
    const int t = threadIdx.x;
    const int bh = blockIdx.y;
    const int b = bh >> 3, h = bh & 7;
    const int t0 = blockIdx.x * 64;
    const int r = t >> 2, c = (t & 3) * 16;

    const u16* src = Vn + (size_t)(b * SB + t0 + r) * DD + h * 64 + c;
    *(u16x8*)&Ls[r][c]     = *(const u16x8*)src;
    *(u16x8*)&Ls[r][c + 8] = *(const u16x8*)(src + 8);
    __syncthreads();

    u16x8 o0, o1;
    #pragma unroll
    for (int jj = 0; jj < 8; ++jj) { o0[jj] = Ls[c + jj][r]; o1[jj] = Ls[c + 8 + jj][r]; }
    u16* dst = Vt + ((size_t)bh * 64 + r) * SB + t0 + c;
    *(u16x8*)dst       = o0;
    *(u16x8*)(dst + 8) = o1;
}

// ---------------------------------------------------------------------------
// Flash attention, barrier-free. Grid (8,8,8), 256 thr / 4 waves; wave w owns
// 32 q-rows (two 16-row MFMA tiles). K/V per (b,h) is 256KB -> L2-resident:
// B-frags loaded DIRECTLY from global (no LDS staging, no __syncthreads).
// K frags prefetched one tile ahead (regs); V frags issued at iter top,
// consumed after softmax; maps prefetched one tile ahead (regs).
// Softmax: DPP max reduce; l-sum deferred to epilogue. P: per-wave LDS.
// ---------------------------------------------------------------------------
__global__ __launch_bounds__(256, 2) void attn_mfma(
    const u16* __restrict__ Qg,   // [b*SB+tok][DD], pre-scaled by 0.125
    const u16* __restrict__ Kg,   // [b*SB+tok][DD]
    const u16* __restrict__ Vt,   // [(b*8+h)*64+dv][tok]
    const float* __restrict__ itg, const float* __restrict__ istg,
    const float* __restrict__ dfg,
    u16* __restrict__ Cg)
{
    const int h  = blockIdx.y;
    const int b  = blockIdx.z;
    const int tid = threadIdx.x;
    const int lane = tid & 63, w = tid >> 6;
    const int l15 = lane & 15, lq = lane >> 4;
    const int qw = blockIdx.x * 128 + w * 32;

    __shared__ __align__(16) u16 Pb[4][32][72];   // per-wave P transpose buffer

    const bool domaps = (h < 6);
    const float* mapsel = (h < 2) ? itg : (h < 4) ? istg : dfg;

    // 32-bit element offsets for map rows (max index 8.4M, fits u32)
    unsigned mrow[8];
    #pragma unroll
    for (int qt = 0; qt < 2; ++qt)
        #pragma unroll
        for (int r = 0; r < 4; ++r)
            mrow[qt * 4 + r] = (unsigned)(b * SB + qw + qt * 16 + lq * 4 + r) * SB + l15;

    // Q A-frags (held whole kernel)
    s16x8 aq[2][2];
    #pragma unroll
    for (int qt = 0; qt < 2; ++qt) {
        const u16* qp = Qg + (size_t)(b * SB + qw + qt * 16 + l15) * DD + h * 64 + lq * 8;
        aq[qt][0] = *(const s16x8*)qp;
        aq[qt][1] = *(const s16x8*)(qp + 32);
    }

    // uniform bases + per-lane 32-bit offsets for K/V B-frag loads
    const u16* Kb = Kg + (size_t)(b * SB) * DD + h * 64;
    const u16* Vb = Vt + ((size_t)(b * 8 + h) * 64) * SB;
    unsigned koff[4], voff[4];
    #pragma unroll
    for (int i = 0; i < 4; ++i) {
        koff[i] = (unsigned)(i * 16 + l15) * DD + lq * 8;
        voff[i] = (unsigned)(i * 16 + l15) * SB + lq * 8;
    }

    s16x8 kr[4][2];
    auto load_k = [&](int k0) {
        #pragma unroll
        for (int nt = 0; nt < 4; ++nt) {
            kr[nt][0] = *(const s16x8*)(Kb + koff[nt] + (unsigned)k0 * DD);
            kr[nt][1] = *(const s16x8*)(Kb + koff[nt] + (unsigned)k0 * DD + 32);
        }
    };
    float mc[32];
    auto load_maps = [&](int k0) {
        #pragma unroll
        for (int i = 0; i < 8; ++i)
            #pragma unroll
            for (int nt = 0; nt < 4; ++nt)
                mc[i * 4 + nt] = mapsel[mrow[i] + (unsigned)k0 + nt * 16];
    };

    f32x4 ctx[2][4] = {};
    float m_i[8], lp[8];
    #pragma unroll
    for (int i = 0; i < 8; ++i) { m_i[i] = -3.0e38f; lp[i] = 0.0f; }

    load_k(0);
    if (domaps) load_maps(0);

    for (int kt = 0; kt < 16; ++kt) {
        const int k0 = kt * 64;

        // ---- V B-frags for this tile: issue early, consume after softmax ----
        s16x8 vr[4][2];
        #pragma unroll
        for (int dvt = 0; dvt < 4; ++dvt) {
            vr[dvt][0] = *(const s16x8*)(Vb + voff[dvt] + (unsigned)k0);
            vr[dvt][1] = *(const s16x8*)(Vb + voff[dvt] + (unsigned)k0 + 32);
        }

        // ---- S = Q K^T from prefetched K frags (shared across qt) ----
        f32x4 S[2][4];
        #pragma unroll
        for (int nt = 0; nt < 4; ++nt) {
            #pragma unroll
            for (int qt = 0; qt < 2; ++qt) {
                f32x4 s = {};
                s = __builtin_amdgcn_mfma_f32_16x16x32_bf16(aq[qt][0], kr[nt][0], s, 0, 0, 0);
                s = __builtin_amdgcn_mfma_f32_16x16x32_bf16(aq[qt][1], kr[nt][1], s, 0, 0, 0);
                S[qt][nt] = s;
            }
        }
        // prefetch K frags for next tile (kr regs just freed)
        if (kt + 1 < 16) load_k(k0 + 64);

        // ---- score modification, then WAR-prefetch next maps ----
        if (h < 4) {
            #pragma unroll
            for (int qt = 0; qt < 2; ++qt)
                #pragma unroll
                for (int nt = 0; nt < 4; ++nt)
                    #pragma unroll
                    for (int r = 0; r < 4; ++r)
                        S[qt][nt][r] += NEGC * mc[(qt * 4 + r) * 4 + nt];
        } else if (h < 6) {
            #pragma unroll
            for (int qt = 0; qt < 2; ++qt)
                #pragma unroll
                for (int nt = 0; nt < 4; ++nt)
                    #pragma unroll
                    for (int r = 0; r < 4; ++r)
                        S[qt][nt][r] *= (1.0f + 5.0f * mc[(qt * 4 + r) * 4 + nt]);
        }
        if (domaps && kt + 1 < 16) load_maps(k0 + 64);

        // ---- online softmax: DPP max reduce; l kept as per-lane partials ----
        #pragma unroll
        for (int qt = 0; qt < 2; ++qt) {
            #pragma unroll
            for (int r = 0; r < 4; ++r) {
                const int i = qt * 4 + r;
                float rm = fmaxf(fmaxf(S[qt][0][r], S[qt][1][r]),
                                 fmaxf(S[qt][2][r], S[qt][3][r]));
                rm = row16_max(rm);
                float mn = fmaxf(m_i[i], rm);
                float al = __expf(m_i[i] - mn);
                m_i[i] = mn;
                float ls = 0.0f;
                #pragma unroll
                for (int nt = 0; nt < 4; ++nt) {
                    float p = __expf(S[qt][nt][r] - mn);
                    S[qt][nt][r] = p;
                    ls += p;
                }
                lp[i] = lp[i] * al + ls;
                #pragma unroll
                for (int nt = 0; nt < 4; ++nt) ctx[qt][nt][r] *= al;
            }
        }

        // ---- P (C-layout) -> per-wave LDS -> A-layout frags (no barrier) ----
        #pragma unroll
        for (int qt = 0; qt < 2; ++qt)
            #pragma unroll
            for (int nt = 0; nt < 4; ++nt)
                #pragma unroll
                for (int r = 0; r < 4; ++r)
                    Pb[w][qt * 16 + lq * 4 + r][nt * 16 + l15] = f2bf(S[qt][nt][r]);
        s16x8 ap[2][2];
        #pragma unroll
        for (int qt = 0; qt < 2; ++qt) {
            ap[qt][0] = *(const s16x8*)&Pb[w][qt * 16 + l15][lq * 8];
            ap[qt][1] = *(const s16x8*)&Pb[w][qt * 16 + l15][32 + lq * 8];
        }

        // ---- ctx += P V (B-frags shared across qt) ----
        #pragma unroll
        for (int dvt = 0; dvt < 4; ++dvt) {
            #pragma unroll
            for (int qt = 0; qt < 2; ++qt) {
                ctx[qt][dvt] = __builtin_amdgcn_mfma_f32_16x16x32_bf16(ap[qt][0], vr[dvt][0], ctx[qt][dvt], 0, 0, 0);
                ctx[qt][dvt] = __builtin_amdgcn_mfma_f32_16x16x32_bf16(ap[qt][1], vr[dvt][1], ctx[qt][dvt], 0, 0, 0);
            }
        }
    }

    // ---- epilogue: one cross-lane l reduce, normalize, store ----
    #pragma unroll
    for (int qt = 0; qt < 2; ++qt) {
        #pragma unroll
        for (int r = 0; r < 4; ++r) {
            const int i = qt * 4 + r;
            float l = row16_sum(lp[i]);
            float inv = (l > 0.0f) ? (1.0f / l) : 0.0f;
            #pragma unroll
            for (int dvt = 0; dvt < 4; ++dvt)
                Cg[(size_t)(b * SB + qw + qt * 16 + lq * 4 + r) * DD + h * 64 + dvt * 16 + l15] =
                    f2bf(ctx[qt][dvt][r] * inv);
        }
    }
}

extern "C" void kernel_launch(void* const* d_in, const int* in_sizes, int n_in,
                              void* d_out, int out_size, void* d_ws, size_t ws_size,
                              hipStream_t stream) {
    const float* key   = (const float*)d_in[0];
    const float* value = (const float*)d_in[1];
    const float* query = (const float*)d_in[2];
    const float* itg   = (const float*)d_in[3];
    const float* istg  = (const float*)d_in[4];
    const float* dfg   = (const float*)d_in[5];
    const float* Wq = (const float*)d_in[7];   const float* bq = (const float*)d_in[8];
    const float* Wk = (const float*)d_in[9];   const float* bk = (const float*)d_in[10];
    const float* Wv = (const float*)d_in[11];  const float* bv = (const float*)d_in[12];
    const float* Wo = (const float*)d_in[13];  const float* bo = (const float*)d_in[14];

    const size_t mat = (size_t)8 * SB * DD;
    if (ws_size < 3 * mat * sizeof(u16)) return;     // known satisfied (r3)

    u16* Kw  = (u16*)d_ws;
    u16* Vtw = Kw + mat;
    u16* Cw  = Vtw + mat;
    u16* Qd  = (u16*)d_out;        // Q bf16 in d_out[0:mat]
    u16* Vn  = Qd + mat;           // V bf16 (untransposed) in d_out[mat:2*mat]

    QKVParams p;
    p.X0 = query; p.X1 = key; p.X2 = value;
    p.W0 = Wq;    p.W1 = Wk;  p.W2 = Wv;
    p.b0 = bq;    p.b1 = bk;  p.b2 = bv;
    p.C0 = Qd;    p.C1 = Kw;  p.C2 = Vn;

    qkv_gemm<<<dim3(DD / 64, (8 * SB) / 128, 3), 256, 0, stream>>>(p);
    vt_kernel<<<dim3(SB / 64, 64), 256, 0, stream>>>(Vn, Vtw);
    attn_mfma<<<dim3(SB / 128, 8, 8), 256, 0, stream>>>(Qd, Kw, Vtw, itg, istg, dfg, Cw);
    out_gemm<<<dim3(DD / 64, (8 * SB) / 128, 1), 256, 0, stream>>>(Cw, Wo, bo, (float*)d_out);
}